// Round 2
// baseline (39.303 us; speedup 1.0000x reference)
//
#include <hip/hip_runtime.h>
#include <math.h>

// QuBlur: x[4096,4096] f32 -> out[2,4096,4096] f32 (real, imag).
// Per 4x4 block: B' = U (B/||B||_F) U^H ; then global /1024.
//
// Global Frobenius norm identity: each normalized block has ||.||_F = 1 and
// unitary conjugation preserves Frobenius norm, so gnorm = sqrt(1024*1024)
// = 1024 exactly (fp deviation ~1e-6 relative -> ~1e-9 absolute on outputs
// of magnitude <= 7.8e-4; threshold is 1.556e-5). This saves a full
// second read+write pass over the 128 MiB output.

#define NQ   4096
#define NBLK 1024

// ---- kernel 1: build the 4x4 complex unitary U from weight[5] ----
__global__ void qblur_setup(const float* __restrict__ wt, float* __restrict__ Ubuf) {
    if (threadIdx.x != 0 || blockIdx.x != 0) return;
    const float W_MUL = 0.6324555320336759f;  // np.float32(sqrt(2)*5^-0.5)
    float c[5], s[5];
    #pragma unroll
    for (int i = 0; i < 5; ++i) {
        float w = wt[i] * W_MUL;
        c[i] = cosf(0.5f * w);
        s[i] = sinf(0.5f * w);
    }
    // 2x2 RY matrices, row-major
    float A1[4] = {c[0], -s[0], s[0], c[0]};
    float B1[4] = {c[1], -s[1], s[1], c[1]};
    float A3[4] = {c[3], -s[3], s[3], c[3]};
    float B3[4] = {c[4], -s[4], s[4], c[4]};
    float g1[16], g3[16];
    for (int i = 0; i < 2; ++i)
        for (int j = 0; j < 2; ++j)
            for (int k = 0; k < 2; ++k)
                for (int l = 0; l < 2; ++l) {
                    g1[(2*i+j)*4 + 2*k+l] = A1[2*i+k] * B1[2*j+l];
                    g3[(2*i+j)*4 + 2*k+l] = A3[2*i+k] * B3[2*j+l];
                }
    // g2 = cos(w2/2) I - i sin(w2/2) * (Y (x) Y); imag = -s2*YY
    float g2r[16], g2i[16];
    for (int i = 0; i < 16; ++i) { g2r[i] = 0.f; g2i[i] = 0.f; }
    g2r[0] = c[2]; g2r[5] = c[2]; g2r[10] = c[2]; g2r[15] = c[2];
    g2i[3] = s[2]; g2i[6] = -s[2]; g2i[9] = -s[2]; g2i[12] = s[2];
    // T = g3 @ g2  (g3 real)  -- match Python's left-assoc (g3@g2)@g1
    float Tr[16], Ti[16];
    for (int i = 0; i < 4; ++i)
        for (int j = 0; j < 4; ++j) {
            float ar = 0.f, ai = 0.f;
            for (int k = 0; k < 4; ++k) {
                ar = fmaf(g3[4*i+k], g2r[4*k+j], ar);
                ai = fmaf(g3[4*i+k], g2i[4*k+j], ai);
            }
            Tr[4*i+j] = ar; Ti[4*i+j] = ai;
        }
    // U = T @ g1  (g1 real)
    for (int i = 0; i < 4; ++i)
        for (int j = 0; j < 4; ++j) {
            float ar = 0.f, ai = 0.f;
            for (int k = 0; k < 4; ++k) {
                ar = fmaf(Tr[4*i+k], g1[4*k+j], ar);
                ai = fmaf(Ti[4*i+k], g1[4*k+j], ai);
            }
            Ubuf[4*i+j]      = ar;  // U real
            Ubuf[16 + 4*i+j] = ai;  // U imag
        }
}

// ---- kernel 2: one thread per 4x4 block ----
__global__ __launch_bounds__(256) void qblur_main(const float* __restrict__ x,
                                                  const float* __restrict__ Ubuf,
                                                  float* __restrict__ out) {
    const int tid = blockIdx.x * 256 + threadIdx.x;   // 0 .. 1048575
    const int a = tid >> 10;                          // block row
    const int b = tid & (NBLK - 1);                   // block col
    const size_t base = (size_t)(a * 4) * NQ + (size_t)b * 4;

    const float* xp = x + base;
    const float4 r0 = *(const float4*)(xp);
    const float4 r1 = *(const float4*)(xp + NQ);
    const float4 r2 = *(const float4*)(xp + 2 * NQ);
    const float4 r3 = *(const float4*)(xp + 3 * NQ);
    float B[4][4] = {
        {r0.x, r0.y, r0.z, r0.w},
        {r1.x, r1.y, r1.z, r1.w},
        {r2.x, r2.y, r2.z, r2.w},
        {r3.x, r3.y, r3.z, r3.w}};

    float ss = 0.f;
    #pragma unroll
    for (int i = 0; i < 4; ++i)
        #pragma unroll
        for (int j = 0; j < 4; ++j) ss = fmaf(B[i][j], B[i][j], ss);
    const float norm = sqrtf(ss);
    // fold per-block norm and global 1/1024 into one scale; zero block -> zeros
    const float scale = (ss > 0.f) ? 1.0f / (norm * 1024.0f) : 0.0f;

    // U is uniform across all threads; L1-broadcast loads
    float Ur[4][4], Ui[4][4];
    #pragma unroll
    for (int i = 0; i < 4; ++i)
        #pragma unroll
        for (int j = 0; j < 4; ++j) {
            Ur[i][j] = Ubuf[4*i+j];
            Ui[i][j] = Ubuf[16 + 4*i+j];
        }

    float* outr = out + base;
    float* outi = out + (size_t)NQ * NQ + base;

    // t = U B U^H, row r of t depends only on row r of M = U B
    #pragma unroll
    for (int r = 0; r < 4; ++r) {
        float mr[4], mi[4];
        #pragma unroll
        for (int cc = 0; cc < 4; ++cc) {
            float ar = 0.f, ai = 0.f;
            #pragma unroll
            for (int k = 0; k < 4; ++k) {
                ar = fmaf(Ur[r][k], B[k][cc], ar);
                ai = fmaf(Ui[r][k], B[k][cc], ai);
            }
            mr[cc] = ar; mi[cc] = ai;
        }
        float trv[4], tiv[4];
        #pragma unroll
        for (int cc = 0; cc < 4; ++cc) {
            float tr = 0.f, ti = 0.f;
            #pragma unroll
            for (int k = 0; k < 4; ++k) {
                // U^H = conj(U)^T : (U^H)[k][cc] = Ur[cc][k] - i Ui[cc][k]
                tr = fmaf(mr[k], Ur[cc][k], tr);
                tr = fmaf(mi[k], Ui[cc][k], tr);
                ti = fmaf(mi[k], Ur[cc][k], ti);
                ti = fmaf(-mr[k], Ui[cc][k], ti);
            }
            trv[cc] = tr * scale;
            tiv[cc] = ti * scale;
        }
        *(float4*)(outr + (size_t)r * NQ) = make_float4(trv[0], trv[1], trv[2], trv[3]);
        *(float4*)(outi + (size_t)r * NQ) = make_float4(tiv[0], tiv[1], tiv[2], tiv[3]);
    }
}

extern "C" void kernel_launch(void* const* d_in, const int* in_sizes, int n_in,
                              void* d_out, int out_size, void* d_ws, size_t ws_size,
                              hipStream_t stream) {
    const float* x  = (const float*)d_in[0];
    const float* wt = (const float*)d_in[1];
    float* out  = (float*)d_out;
    float* Ubuf = (float*)d_ws;   // 32 floats

    qblur_setup<<<1, 64, 0, stream>>>(wt, Ubuf);

    const int n_threads = NBLK * NBLK;          // one thread per 4x4 block
    qblur_main<<<n_threads / 256, 256, 0, stream>>>(x, Ubuf, out);
}

// Round 4
// 36.312 us; speedup vs baseline: 1.0824x; 1.0824x over previous
//
#include <hip/hip_runtime.h>
#include <math.h>

// QuBlur: x[4096,4096] f32 -> out[2,4096,4096] f32 (real, imag).
// Per 4x4 block: B' = U (B/||B||_F) U^H ; then global /1024.
//
// gnorm identity: normalized blocks have ||.||_F = 1, unitary conjugation
// preserves it -> gnorm = 1024 analytically (error ~1e-9 abs vs 1.56e-5
// threshold). Saves the second full pass over the 128 MiB output.
//
// R2: fused U-computation (thread 0 per wg -> LDS broadcast) removes the
// separate setup launch; nontemporal output stores keep x L3-resident.
// R3: nontemporal builtin needs a native vector type, not HIP float4.

#define NQ   4096
#define NBLK 1024

typedef float f32x4 __attribute__((ext_vector_type(4)));

__global__ __launch_bounds__(256) void qblur_main(const float* __restrict__ x,
                                                  const float* __restrict__ wt,
                                                  float* __restrict__ out) {
    __shared__ float Uld[32];   // [0:16) = U real, [16:32) = U imag

    if (threadIdx.x == 0) {
        const float W_MUL = 0.6324555320336759f;  // np.float32(sqrt(2)*5^-0.5)
        float c[5], s[5];
        #pragma unroll
        for (int i = 0; i < 5; ++i) {
            float w = wt[i] * W_MUL;
            c[i] = cosf(0.5f * w);
            s[i] = sinf(0.5f * w);
        }
        float A1[4] = {c[0], -s[0], s[0], c[0]};
        float B1[4] = {c[1], -s[1], s[1], c[1]};
        float A3[4] = {c[3], -s[3], s[3], c[3]};
        float B3[4] = {c[4], -s[4], s[4], c[4]};
        float g1[16], g3[16];
        for (int i = 0; i < 2; ++i)
            for (int j = 0; j < 2; ++j)
                for (int k = 0; k < 2; ++k)
                    for (int l = 0; l < 2; ++l) {
                        g1[(2*i+j)*4 + 2*k+l] = A1[2*i+k] * B1[2*j+l];
                        g3[(2*i+j)*4 + 2*k+l] = A3[2*i+k] * B3[2*j+l];
                    }
        // g2 = cos(w2/2) I - i sin(w2/2) * (Y (x) Y)
        float g2r[16], g2i[16];
        for (int i = 0; i < 16; ++i) { g2r[i] = 0.f; g2i[i] = 0.f; }
        g2r[0] = c[2]; g2r[5] = c[2]; g2r[10] = c[2]; g2r[15] = c[2];
        g2i[3] = s[2]; g2i[6] = -s[2]; g2i[9] = -s[2]; g2i[12] = s[2];
        // T = g3 @ g2 (left-assoc like the reference), then U = T @ g1
        float Tr[16], Ti[16];
        for (int i = 0; i < 4; ++i)
            for (int j = 0; j < 4; ++j) {
                float ar = 0.f, ai = 0.f;
                for (int k = 0; k < 4; ++k) {
                    ar = fmaf(g3[4*i+k], g2r[4*k+j], ar);
                    ai = fmaf(g3[4*i+k], g2i[4*k+j], ai);
                }
                Tr[4*i+j] = ar; Ti[4*i+j] = ai;
            }
        for (int i = 0; i < 4; ++i)
            for (int j = 0; j < 4; ++j) {
                float ar = 0.f, ai = 0.f;
                for (int k = 0; k < 4; ++k) {
                    ar = fmaf(Tr[4*i+k], g1[4*k+j], ar);
                    ai = fmaf(Ti[4*i+k], g1[4*k+j], ai);
                }
                Uld[4*i+j]      = ar;
                Uld[16 + 4*i+j] = ai;
            }
    }
    __syncthreads();

    const int tid = blockIdx.x * 256 + threadIdx.x;   // 0 .. 1048575
    const int a = tid >> 10;                          // block row
    const int b = tid & (NBLK - 1);                   // block col
    const size_t base = (size_t)(a * 4) * NQ + (size_t)b * 4;

    const float* xp = x + base;
    const float4 r0 = *(const float4*)(xp);
    const float4 r1 = *(const float4*)(xp + NQ);
    const float4 r2 = *(const float4*)(xp + 2 * NQ);
    const float4 r3 = *(const float4*)(xp + 3 * NQ);
    float B[4][4] = {
        {r0.x, r0.y, r0.z, r0.w},
        {r1.x, r1.y, r1.z, r1.w},
        {r2.x, r2.y, r2.z, r2.w},
        {r3.x, r3.y, r3.z, r3.w}};

    float ss = 0.f;
    #pragma unroll
    for (int i = 0; i < 4; ++i)
        #pragma unroll
        for (int j = 0; j < 4; ++j) ss = fmaf(B[i][j], B[i][j], ss);
    const float norm = sqrtf(ss);
    const float scale = (ss > 0.f) ? 1.0f / (norm * 1024.0f) : 0.0f;

    // uniform-address LDS reads -> broadcast, no bank conflicts
    float Ur[4][4], Ui[4][4];
    #pragma unroll
    for (int i = 0; i < 4; ++i)
        #pragma unroll
        for (int j = 0; j < 4; ++j) {
            Ur[i][j] = Uld[4*i+j];
            Ui[i][j] = Uld[16 + 4*i+j];
        }

    float* outr = out + base;
    float* outi = out + (size_t)NQ * NQ + base;

    // t = U B U^H; row r of t depends only on row r of M = U B
    #pragma unroll
    for (int r = 0; r < 4; ++r) {
        float mr[4], mi[4];
        #pragma unroll
        for (int cc = 0; cc < 4; ++cc) {
            float ar = 0.f, ai = 0.f;
            #pragma unroll
            for (int k = 0; k < 4; ++k) {
                ar = fmaf(Ur[r][k], B[k][cc], ar);
                ai = fmaf(Ui[r][k], B[k][cc], ai);
            }
            mr[cc] = ar; mi[cc] = ai;
        }
        f32x4 trv, tiv;
        #pragma unroll
        for (int cc = 0; cc < 4; ++cc) {
            float tr = 0.f, ti = 0.f;
            #pragma unroll
            for (int k = 0; k < 4; ++k) {
                // (U^H)[k][cc] = Ur[cc][k] - i Ui[cc][k]
                tr = fmaf(mr[k], Ur[cc][k], tr);
                tr = fmaf(mi[k], Ui[cc][k], tr);
                ti = fmaf(mi[k], Ur[cc][k], ti);
                ti = fmaf(-mr[k], Ui[cc][k], ti);
            }
            trv[cc] = tr * scale;
            tiv[cc] = ti * scale;
        }
        __builtin_nontemporal_store(trv, (f32x4*)(outr + (size_t)r * NQ));
        __builtin_nontemporal_store(tiv, (f32x4*)(outi + (size_t)r * NQ));
    }
}

extern "C" void kernel_launch(void* const* d_in, const int* in_sizes, int n_in,
                              void* d_out, int out_size, void* d_ws, size_t ws_size,
                              hipStream_t stream) {
    const float* x  = (const float*)d_in[0];
    const float* wt = (const float*)d_in[1];
    float* out = (float*)d_out;

    const int n_threads = NBLK * NBLK;          // one thread per 4x4 block
    qblur_main<<<n_threads / 256, 256, 0, stream>>>(x, wt, out);
}

// Round 5
// 36.252 us; speedup vs baseline: 1.0841x; 1.0017x over previous
//
#include <hip/hip_runtime.h>
#include <math.h>

// QuBlur: x[4096,4096] f32 -> out[2,4096,4096] f32 (real, imag).
// Per 4x4 block: B' = U (B/||B||_F) U^H ; then global /1024.
//
// gnorm identity: normalized blocks have ||.||_F = 1, unitary conjugation
// preserves it -> gnorm = 1024 analytically (error ~1e-9 abs vs 1.56e-5
// threshold). Saves the second full pass over the 128 MiB output.
//
// R2: fused U-computation (thread 0 per wg -> LDS broadcast), one dispatch.
// R5: REVERT nontemporal stores — nt bypasses L2 write-combining and capped
//     write BW at ~3.5 TB/s (fill kernel shows 7 TB/s with normal stores).
//     L3 residency of x doesn't need nt: 128MB out + 64MB x < 256MB L3.

#define NQ   4096
#define NBLK 1024

typedef float f32x4 __attribute__((ext_vector_type(4)));

__global__ __launch_bounds__(256) void qblur_main(const float* __restrict__ x,
                                                  const float* __restrict__ wt,
                                                  float* __restrict__ out) {
    __shared__ float Uld[32];   // [0:16) = U real, [16:32) = U imag

    if (threadIdx.x == 0) {
        const float W_MUL = 0.6324555320336759f;  // np.float32(sqrt(2)*5^-0.5)
        float c[5], s[5];
        #pragma unroll
        for (int i = 0; i < 5; ++i) {
            float w = wt[i] * W_MUL;
            c[i] = cosf(0.5f * w);
            s[i] = sinf(0.5f * w);
        }
        float A1[4] = {c[0], -s[0], s[0], c[0]};
        float B1[4] = {c[1], -s[1], s[1], c[1]};
        float A3[4] = {c[3], -s[3], s[3], c[3]};
        float B3[4] = {c[4], -s[4], s[4], c[4]};
        float g1[16], g3[16];
        for (int i = 0; i < 2; ++i)
            for (int j = 0; j < 2; ++j)
                for (int k = 0; k < 2; ++k)
                    for (int l = 0; l < 2; ++l) {
                        g1[(2*i+j)*4 + 2*k+l] = A1[2*i+k] * B1[2*j+l];
                        g3[(2*i+j)*4 + 2*k+l] = A3[2*i+k] * B3[2*j+l];
                    }
        // g2 = cos(w2/2) I - i sin(w2/2) * (Y (x) Y)
        float g2r[16], g2i[16];
        for (int i = 0; i < 16; ++i) { g2r[i] = 0.f; g2i[i] = 0.f; }
        g2r[0] = c[2]; g2r[5] = c[2]; g2r[10] = c[2]; g2r[15] = c[2];
        g2i[3] = s[2]; g2i[6] = -s[2]; g2i[9] = -s[2]; g2i[12] = s[2];
        // T = g3 @ g2 (left-assoc like the reference), then U = T @ g1
        float Tr[16], Ti[16];
        for (int i = 0; i < 4; ++i)
            for (int j = 0; j < 4; ++j) {
                float ar = 0.f, ai = 0.f;
                for (int k = 0; k < 4; ++k) {
                    ar = fmaf(g3[4*i+k], g2r[4*k+j], ar);
                    ai = fmaf(g3[4*i+k], g2i[4*k+j], ai);
                }
                Tr[4*i+j] = ar; Ti[4*i+j] = ai;
            }
        for (int i = 0; i < 4; ++i)
            for (int j = 0; j < 4; ++j) {
                float ar = 0.f, ai = 0.f;
                for (int k = 0; k < 4; ++k) {
                    ar = fmaf(Tr[4*i+k], g1[4*k+j], ar);
                    ai = fmaf(Ti[4*i+k], g1[4*k+j], ai);
                }
                Uld[4*i+j]      = ar;
                Uld[16 + 4*i+j] = ai;
            }
    }
    __syncthreads();

    const int tid = blockIdx.x * 256 + threadIdx.x;   // 0 .. 1048575
    const int a = tid >> 10;                          // block row
    const int b = tid & (NBLK - 1);                   // block col
    const size_t base = (size_t)(a * 4) * NQ + (size_t)b * 4;

    const float* xp = x + base;
    const float4 r0 = *(const float4*)(xp);
    const float4 r1 = *(const float4*)(xp + NQ);
    const float4 r2 = *(const float4*)(xp + 2 * NQ);
    const float4 r3 = *(const float4*)(xp + 3 * NQ);
    float B[4][4] = {
        {r0.x, r0.y, r0.z, r0.w},
        {r1.x, r1.y, r1.z, r1.w},
        {r2.x, r2.y, r2.z, r2.w},
        {r3.x, r3.y, r3.z, r3.w}};

    float ss = 0.f;
    #pragma unroll
    for (int i = 0; i < 4; ++i)
        #pragma unroll
        for (int j = 0; j < 4; ++j) ss = fmaf(B[i][j], B[i][j], ss);
    const float norm = sqrtf(ss);
    const float scale = (ss > 0.f) ? 1.0f / (norm * 1024.0f) : 0.0f;

    // uniform-address LDS reads -> broadcast, no bank conflicts
    float Ur[4][4], Ui[4][4];
    #pragma unroll
    for (int i = 0; i < 4; ++i)
        #pragma unroll
        for (int j = 0; j < 4; ++j) {
            Ur[i][j] = Uld[4*i+j];
            Ui[i][j] = Uld[16 + 4*i+j];
        }

    float* outr = out + base;
    float* outi = out + (size_t)NQ * NQ + base;

    // t = U B U^H; row r of t depends only on row r of M = U B
    #pragma unroll
    for (int r = 0; r < 4; ++r) {
        float mr[4], mi[4];
        #pragma unroll
        for (int cc = 0; cc < 4; ++cc) {
            float ar = 0.f, ai = 0.f;
            #pragma unroll
            for (int k = 0; k < 4; ++k) {
                ar = fmaf(Ur[r][k], B[k][cc], ar);
                ai = fmaf(Ui[r][k], B[k][cc], ai);
            }
            mr[cc] = ar; mi[cc] = ai;
        }
        f32x4 trv, tiv;
        #pragma unroll
        for (int cc = 0; cc < 4; ++cc) {
            float tr = 0.f, ti = 0.f;
            #pragma unroll
            for (int k = 0; k < 4; ++k) {
                // (U^H)[k][cc] = Ur[cc][k] - i Ui[cc][k]
                tr = fmaf(mr[k], Ur[cc][k], tr);
                tr = fmaf(mi[k], Ui[cc][k], tr);
                ti = fmaf(mi[k], Ur[cc][k], ti);
                ti = fmaf(-mr[k], Ui[cc][k], ti);
            }
            trv[cc] = tr * scale;
            tiv[cc] = ti * scale;
        }
        *(f32x4*)(outr + (size_t)r * NQ) = trv;
        *(f32x4*)(outi + (size_t)r * NQ) = tiv;
    }
}

extern "C" void kernel_launch(void* const* d_in, const int* in_sizes, int n_in,
                              void* d_out, int out_size, void* d_ws, size_t ws_size,
                              hipStream_t stream) {
    const float* x  = (const float*)d_in[0];
    const float* wt = (const float*)d_in[1];
    float* out = (float*)d_out;

    const int n_threads = NBLK * NBLK;          // one thread per 4x4 block
    qblur_main<<<n_threads / 256, 256, 0, stream>>>(x, wt, out);
}